// Round 6
// baseline (1954.118 us; speedup 1.0000x reference)
//
#include <hip/hip_runtime.h>
#include <math.h>

#define NBATCH 4
#define DIM    1024
#define NHEAD  4
#define HD     256
#define NQ     1024
#define MASKN  2304           // 48*48
#define NMAX   3329           // 1024 query + 1 sep + 2304 max prompts
#define TWO_PI 6.283185307179586f

typedef unsigned short bf16_t;
typedef short bf16x8 __attribute__((ext_vector_type(8)));
typedef float f32x4  __attribute__((ext_vector_type(4)));

__device__ __forceinline__ float gelu_exact(float x) {
    return 0.5f * x * (1.0f + erff(x * 0.70710678118654752f));
}
__device__ __forceinline__ float bf2f(bf16_t h) {
    return __uint_as_float((unsigned)h << 16);
}
__device__ __forceinline__ bf16_t f2bf(float f) {   // round-to-nearest-even
    unsigned u = __float_as_uint(f);
    return (bf16_t)((u + 0x7FFFu + ((u >> 16) & 1u)) >> 16);
}

// ---------------------------------------------------------------- compaction
__global__ __launch_bounds__(256)
void k_compact(const int* __restrict__ mask, int* __restrict__ cnt, int* __restrict__ pidx) {
    int b = blockIdx.x;
    __shared__ int sc;
    if (threadIdx.x == 0) sc = 0;
    __syncthreads();
    for (int c = threadIdx.x; c < MASKN; c += blockDim.x)
        if (mask[b * MASKN + c] > 0) {
            int p = atomicAdd(&sc, 1);
            pidx[b * MASKN + p] = c;
        }
    __syncthreads();
    if (threadIdx.x == 0) cnt[b] = sc;
}

__global__ __launch_bounds__(256)
void k_zerobias(float* __restrict__ z) {
    z[blockIdx.x * 256 + threadIdx.x] = 0.f;
}

// ---------------------------------- weight transpose-convert: W(KxN f32)->Wt(NxK bf16)
__global__ __launch_bounds__(256)
void k_wt(const float* __restrict__ W, bf16_t* __restrict__ Wt, int K, int N) {
    __shared__ float T[64][65];
    int n0 = blockIdx.x * 64, k0 = blockIdx.y * 64;
    int tid = threadIdx.x;
    int lr = tid >> 4, lc = (tid & 15) * 4;
    #pragma unroll
    for (int i = 0; i < 4; ++i) {
        float4 v = *(const float4*)&W[(size_t)(k0 + lr + i * 16) * N + n0 + lc];
        T[lr + i * 16][lc + 0] = v.x; T[lr + i * 16][lc + 1] = v.y;
        T[lr + i * 16][lc + 2] = v.z; T[lr + i * 16][lc + 3] = v.w;
    }
    __syncthreads();
    int on = tid >> 2, ok = (tid & 3) * 16;
    bf16_t tmp[16];
    #pragma unroll
    for (int j = 0; j < 16; ++j) tmp[j] = f2bf(T[ok + j][on]);
    bf16_t* op = Wt + (size_t)(n0 + on) * K + k0 + ok;
    *(bf16x8*)op       = *(bf16x8*)&tmp[0];
    *(bf16x8*)(op + 8) = *(bf16x8*)&tmp[8];
}

// ------------------------------------------------- query tokens: emb + PE (f32 X)
__global__ __launch_bounds__(256)
void k_init_query(const float* __restrict__ emb, const float* __restrict__ gauss,
                  float* __restrict__ X) {
    int b = blockIdx.y, n = blockIdx.x, t = threadIdx.x;
    float fx = 2.0f * (((n & 31) + 0.5f) / 32.0f) - 1.0f;
    float fy = 2.0f * (((n >> 5) + 0.5f) / 32.0f) - 1.0f;
    const float* e = emb + ((size_t)b * NQ + n) * DIM;
    float* x = X + ((size_t)b * NMAX + n) * DIM;
    for (int d = t; d < 512; d += 256) {
        float ang = TWO_PI * (fx * gauss[d] + fy * gauss[512 + d]);
        float sn, cs; sincosf(ang, &sn, &cs);
        x[d]       = e[d] + sn;
        x[d + 512] = e[d + 512] + cs;
    }
}

// --------------------------------- prompt hidden: gelu(d*w1+b1) (M x 512) bf16
__global__ __launch_bounds__(256)
void k_prompt_h(const float* __restrict__ depth, const float* __restrict__ w1,
                const float* __restrict__ b1, const int* __restrict__ cnt,
                const int* __restrict__ pidx, bf16_t* __restrict__ Hp) {
    int b = blockIdx.y, s = blockIdx.x, t = threadIdx.x;
    bf16_t* hp = Hp + ((size_t)b * MASKN + s) * 512;
    if (s >= cnt[b]) { hp[t] = 0; hp[t + 256] = 0; return; }
    int cell = pidx[b * MASKN + s];
    float d = depth[b * MASKN + cell];
    for (int j = t; j < 512; j += 256)
        hp[j] = f2bf(gelu_exact(fmaf(d, w1[j], b1[j])));
}

// ------------------------------------------ add prompt PE into X rows (f32)
__global__ __launch_bounds__(256)
void k_pe_prompt(const float* __restrict__ gauss, const int* __restrict__ cnt,
                 const int* __restrict__ pidx, float* __restrict__ X) {
    int b = blockIdx.y, s = blockIdx.x, t = threadIdx.x;
    if (s >= cnt[b]) return;
    int cell = pidx[b * MASKN + s];
    int r = cell / 48, c = cell % 48;
    float fx = 2.0f * ((c + 0.5f) / 48.0f) - 1.0f;
    float fy = 2.0f * ((r + 0.5f) / 48.0f) - 1.0f;
    float* x = X + ((size_t)b * NMAX + 1025 + s) * DIM;
    for (int d = t; d < 512; d += 256) {
        float ang = TWO_PI * (fx * gauss[d] + fy * gauss[512 + d]);
        float sn, cs; sincosf(ang, &sn, &cs);
        x[d]       += sn;
        x[d + 512] += cs;
    }
}

// ---------------------------------------------------------------- sep token
__global__ __launch_bounds__(256)
void k_sep(float* __restrict__ X, const float* __restrict__ sep) {
    int b = blockIdx.x, t = threadIdx.x;
    float* x = X + ((size_t)b * NMAX + 1024) * DIM;
    *(float4*)&x[t * 4] = *(const float4*)&sep[t * 4];
}

// -------------------------------------------------- layernorm: X f32 -> Xn bf16
__global__ __launch_bounds__(256)
void k_ln(const float* __restrict__ X, bf16_t* __restrict__ Xn,
          const float* __restrict__ w, const float* __restrict__ bb,
          const int* __restrict__ cnt) {
    int b = blockIdx.y, n = blockIdx.x;
    int Nb = 1025 + cnt[b];
    if (n >= Nb) return;
    int t = threadIdx.x;
    const float* x = X + ((size_t)b * NMAX + n) * DIM;
    float4 v = *(const float4*)&x[t * 4];
    float s = v.x + v.y + v.z + v.w;
    float q = v.x * v.x + v.y * v.y + v.z * v.z + v.w * v.w;
    #pragma unroll
    for (int off = 32; off > 0; off >>= 1) {
        s += __shfl_xor(s, off);
        q += __shfl_xor(q, off);
    }
    __shared__ float ss[4], sq[4];
    int wave = t >> 6, lane = t & 63;
    if (lane == 0) { ss[wave] = s; sq[wave] = q; }
    __syncthreads();
    s = ss[0] + ss[1] + ss[2] + ss[3];
    q = sq[0] + sq[1] + sq[2] + sq[3];
    float mean = s * (1.0f / DIM);
    float var  = q * (1.0f / DIM) - mean * mean;
    float rstd = 1.0f / sqrtf(var + 1e-5f);
    float4 ww = *(const float4*)&w[t * 4];
    float4 b4 = *(const float4*)&bb[t * 4];
    ushort4 o;
    o.x = f2bf((v.x - mean) * rstd * ww.x + b4.x);
    o.y = f2bf((v.y - mean) * rstd * ww.y + b4.y);
    o.z = f2bf((v.z - mean) * rstd * ww.z + b4.z);
    o.w = f2bf((v.w - mean) * rstd * ww.w + b4.w);
    *(ushort4*)&(Xn + ((size_t)b * NMAX + n) * DIM)[t * 4] = o;
}

// ================================ MFMA GEMM: A bf16 @ Wt bf16 (pre-transposed)
template <int EPI, typename OutT>
__global__ __launch_bounds__(256)
void k_gemm_bt(const bf16_t* __restrict__ A, size_t bsA, int ldA,
               const bf16_t* __restrict__ Wt, int ldWt, const float* __restrict__ bias,
               OutT* __restrict__ Out, size_t bsO, int ldO,
               int K, const int* __restrict__ cnt, int bound_add, int rows_phys) {
    int b = blockIdx.z;
    int bound = cnt[b] + bound_add;
    int tr = blockIdx.y * 128;
    if (tr >= bound) return;
    int tc = blockIdx.x * 128;

    __shared__ bf16_t As[128][72];   // 64 k + 8 pad
    __shared__ bf16_t Bs[128][72];

    int tid  = threadIdx.x;
    int wave = tid >> 6, lane = tid & 63;
    int quad = lane >> 4, l16 = lane & 15;
    int wr = (wave >> 1) * 64, wc = (wave & 1) * 64;

    f32x4 acc[4][4];
    #pragma unroll
    for (int mi = 0; mi < 4; ++mi)
        #pragma unroll
        for (int ni = 0; ni < 4; ++ni)
            acc[mi][ni] = (f32x4){0.f, 0.f, 0.f, 0.f};

    const bf16_t* Ab = A + (size_t)b * bsA;
    int sr = tid >> 1;
    int sc = (tid & 1) * 32;

    for (int k0 = 0; k0 < K; k0 += 64) {
        __syncthreads();
        {
            int row = tr + sr;
            bf16x8 v[4];
            #pragma unroll
            for (int j = 0; j < 4; ++j) v[j] = (bf16x8){0,0,0,0,0,0,0,0};
            if (row < rows_phys) {
                const bf16_t* ap = Ab + (size_t)row * ldA + k0 + sc;
                #pragma unroll
                for (int j = 0; j < 4; ++j) v[j] = *(const bf16x8*)(ap + j * 8);
            }
            #pragma unroll
            for (int j = 0; j < 4; ++j) *(bf16x8*)&As[sr][sc + j * 8] = v[j];
        }
        {
            const bf16_t* bp = Wt + (size_t)(tc + sr) * ldWt + k0 + sc;
            #pragma unroll
            for (int j = 0; j < 4; ++j)
                *(bf16x8*)&Bs[sr][sc + j * 8] = *(const bf16x8*)(bp + j * 8);
        }
        __syncthreads();

        #pragma unroll
        for (int half = 0; half < 2; ++half) {
            int ko = half * 32 + quad * 8;
            bf16x8 af[4], bfr[4];
            #pragma unroll
            for (int mi = 0; mi < 4; ++mi)
                af[mi] = *(const bf16x8*)&As[wr + mi * 16 + l16][ko];
            #pragma unroll
            for (int ni = 0; ni < 4; ++ni)
                bfr[ni] = *(const bf16x8*)&Bs[wc + ni * 16 + l16][ko];
            #pragma unroll
            for (int mi = 0; mi < 4; ++mi)
                #pragma unroll
                for (int ni = 0; ni < 4; ++ni)
                    acc[mi][ni] = __builtin_amdgcn_mfma_f32_16x16x32_bf16(
                        af[mi], bfr[ni], acc[mi][ni], 0, 0, 0);
        }
    }

    OutT* Ob = Out + (size_t)b * bsO;
    #pragma unroll
    for (int ni = 0; ni < 4; ++ni) {
        int col = tc + wc + ni * 16 + l16;
        float bs = bias[col];
        #pragma unroll
        for (int mi = 0; mi < 4; ++mi) {
            int row0 = tr + wr + mi * 16 + quad * 4;
            #pragma unroll
            for (int r = 0; r < 4; ++r) {
                int row = row0 + r;
                if (row >= rows_phys) continue;
                float v = acc[mi][ni][r] + bs;
                if (EPI == 1) v = gelu_exact(v);
                OutT* op = Ob + (size_t)row * ldO + col;
                if (EPI == 2) v += *(const float*)op;
                if (sizeof(OutT) == 2) *(bf16_t*)op = f2bf(v);
                else                   *(float*)op  = v;
            }
        }
    }
}

// =================================================== MFMA flash attention
// 128 Q rows/WG, 512 threads (8 waves x 16 rows). K-tile 32 keys row-major;
// V-tile transposed with 8-aligned XOR swizzle: Vt[dim][key ^ ((dim>>3)&3)*8]
// -> staging writes 2-way (free), b128 reads stay contiguous & de-aliased.
__global__ __launch_bounds__(512)
void k_attn_mfma(const bf16_t* __restrict__ QKV, bf16_t* __restrict__ O,
                 const int* __restrict__ cnt) {
    int b = blockIdx.z, h = blockIdx.y;
    int Nb = 1025 + cnt[b];
    int qbase = blockIdx.x * 128;
    if (qbase >= Nb) return;

    __shared__ bf16_t Kt[32][264];      // 16.9 KB
    __shared__ bf16_t Vt[256][40];      // 20.5 KB, swizzled cols
    __shared__ bf16_t Pt[8][16][40];    // 10.2 KB per-wave P

    int tid  = threadIdx.x;
    int wave = tid >> 6, lane = tid & 63;
    int quad = lane >> 4, l16 = lane & 15;

    int qrow  = qbase + wave * 16 + l16;
    int qrowc = qrow < NMAX ? qrow : NMAX - 1;
    const bf16_t* Qp = QKV + (size_t)b * NMAX * 3072 + (size_t)qrowc * 3072 + h * HD;
    bf16x8 qf[8];
    #pragma unroll
    for (int c = 0; c < 8; ++c)
        qf[c] = *(const bf16x8*)(Qp + c * 32 + quad * 8);

    f32x4 Oacc[16];
    #pragma unroll
    for (int n = 0; n < 16; ++n) Oacc[n] = (f32x4){0.f, 0.f, 0.f, 0.f};
    float l[4] = {0.f, 0.f, 0.f, 0.f};

    const bf16_t* Kg = QKV + (size_t)b * NMAX * 3072 + 1024 + h * HD;
    const bf16_t* Vg = QKV + (size_t)b * NMAX * 3072 + 2048 + h * HD;

    // staging assignments (512 threads)
    int krow_s = tid >> 4;            // K: row 0..31, dims (tid&15)*16 .. +15
    int kd_s   = (tid & 15) * 16;
    int vdg    = tid >> 4;            // V: dims vdg*8..+7, keys kp, kp+1
    int vkp    = (tid & 15) * 2;
    int vsw    = (vdg & 3) * 8;       // swizzle for this thread's dim group

    for (int kt = 0; kt < Nb; kt += 32) {
        __syncthreads();
        {   // K tile
            int gk = kt + krow_s;
            bf16x8 v0 = (bf16x8){0,0,0,0,0,0,0,0};
            bf16x8 v1 = (bf16x8){0,0,0,0,0,0,0,0};
            if (gk < Nb) {
                const bf16_t* kp = Kg + (size_t)gk * 3072 + kd_s;
                v0 = *(const bf16x8*)kp;
                v1 = *(const bf16x8*)(kp + 8);
            }
            *(bf16x8*)&Kt[krow_s][kd_s]     = v0;
            *(bf16x8*)&Kt[krow_s][kd_s + 8] = v1;
        }
        {   // V tile transposed, swizzled
            int g0 = kt + vkp, g1 = kt + vkp + 1;
            bf16x8 r0 = (bf16x8){0,0,0,0,0,0,0,0};
            bf16x8 r1 = (bf16x8){0,0,0,0,0,0,0,0};
            if (g0 < Nb) r0 = *(const bf16x8*)(Vg + (size_t)g0 * 3072 + vdg * 8);
            if (g1 < Nb) r1 = *(const bf16x8*)(Vg + (size_t)g1 * 3072 + vdg * 8);
            int colw = vkp ^ vsw;
            #pragma unroll
            for (int j = 0; j < 8; ++j) {
                ushort2 pk;
                pk.x = (unsigned short)r0[j];
                pk.y = (unsigned short)r1[j];
                *(ushort2*)&Vt[vdg * 8 + j][colw] = pk;
            }
        }
        __syncthreads();

        // S = Q.K^T
        f32x4 c0 = (f32x4){0.f,0.f,0.f,0.f}, c1 = (f32x4){0.f,0.f,0.f,0.f};
        #pragma unroll
        for (int c = 0; c < 8; ++c) {
            bf16x8 kb0 = *(const bf16x8*)&Kt[l16     ][c * 32 + quad * 8];
            bf16x8 kb1 = *(const bf16x8*)&Kt[l16 + 16][c * 32 + quad * 8];
            c0 = __builtin_amdgcn_mfma_f32_16x16x32_bf16(qf[c], kb0, c0, 0, 0, 0);
            c1 = __builtin_amdgcn_mfma_f32_16x16x32_bf16(qf[c], kb1, c1, 0, 0, 0);
        }
        float ls[4];
        #pragma unroll
        for (int r = 0; r < 4; ++r) {
            float p0 = (kt + l16      < Nb) ? __expf(c0[r] * 0.0625f) : 0.f;
            float p1 = (kt + 16 + l16 < Nb) ? __expf(c1[r] * 0.0625f) : 0.f;
            Pt[wave][quad * 4 + r][l16]      = f2bf(p0);
            Pt[wave][quad * 4 + r][l16 + 16] = f2bf(p1);
            ls[r] = p0 + p1;
        }
        #pragma unroll
        for (int off = 1; off < 16; off <<= 1)
            #pragma unroll
            for (int r = 0; r < 4; ++r)
                ls[r] += __shfl_xor(ls[r], off);
        #pragma unroll
        for (int r = 0; r < 4; ++r) l[r] += ls[r];

        // P.V with swizzled B-frag reads
        bf16x8 pa = *(const bf16x8*)&Pt[wave][l16][quad * 8];
        #pragma unroll
        for (int n = 0; n < 16; ++n) {
            int sv = ((n * 2 + (l16 >> 3)) & 3) * 8;
            bf16x8 vb = *(const bf16x8*)&Vt[n * 16 + l16][(quad * 8) ^ sv];
            Oacc[n] = __builtin_amdgcn_mfma_f32_16x16x32_bf16(pa, vb, Oacc[n], 0, 0, 0);
        }
    }

    float inv[4];
    #pragma unroll
    for (int r = 0; r < 4; ++r) inv[r] = 1.0f / l[r];
    bf16_t* Op = O + (size_t)b * NMAX * DIM + h * HD;
    #pragma unroll
    for (int r = 0; r < 4; ++r) {
        int row = qbase + wave * 16 + quad * 4 + r;
        if (row < Nb) {
            bf16_t* op = Op + (size_t)row * DIM;
            #pragma unroll
            for (int n = 0; n < 16; ++n)
                op[n * 16 + l16] = f2bf(Oacc[n][r] * inv[r]);
        }
    }
}

// ---------------------------------------------------------------- output
__global__ __launch_bounds__(256)
void k_out(const float* __restrict__ X, const float* __restrict__ emb,
           const int* __restrict__ cnt, float* __restrict__ out) {
    int b = blockIdx.y, n = blockIdx.x, t = threadIdx.x;
    const float* s = (cnt[b] > 0) ? X + ((size_t)b * NMAX + n) * DIM
                                  : emb + ((size_t)b * NQ + n) * DIM;
    *(float4*)&out[((size_t)b * NQ + n) * DIM + t * 4] = *(const float4*)&s[t * 4];
}

// ============================================================== launch
extern "C" void kernel_launch(void* const* d_in, const int* in_sizes, int n_in,
                              void* d_out, int out_size, void* d_ws, size_t ws_size,
                              hipStream_t stream) {
    const float* emb    = (const float*)d_in[0];
    const float* depth  = (const float*)d_in[1];
    const int*   mask   = (const int*)d_in[2];
    const float* gauss  = (const float*)d_in[5];
    const float* d2f_w1 = (const float*)d_in[6];
    const float* d2f_b1 = (const float*)d_in[7];
    const float* d2f_w2 = (const float*)d_in[8];
    const float* d2f_b2 = (const float*)d_in[9];
    const float* sep    = (const float*)d_in[10];
    const float* ln1_w  = (const float*)d_in[11];
    const float* ln1_b  = (const float*)d_in[12];
    const float* qkv_w  = (const float*)d_in[13];
    const float* qkv_b  = (const float*)d_in[14];
    const float* proj_w = (const float*)d_in[15];
    const float* proj_b = (const float*)d_in[16];
    const float* ln2_w  = (const float*)d_in[17];
    const float* ln2_b  = (const float*)d_in[18];
    const float* mlp_w1 = (const float*)d_in[19];
    const float* mlp_b1 = (const float*)d_in[20];
    const float* mlp_w2 = (const float*)d_in[21];
    const float* mlp_b2 = (const float*)d_in[22];
    float* out = (float*)d_out;

    char* wsb = (char*)d_ws;
    int*    cnt   = (int*)wsb;
    int*    pidx  = (int*)(wsb + 256);
    float*  zbias = (float*)(wsb + 37120);
    float*  X     = (float*)(wsb + 41216);
    bf16_t* Xn    = (bf16_t*)(wsb + 54583552);
    bf16_t* Qb    = (bf16_t*)(wsb + 81854720);
    bf16_t* Wt_qkv = (bf16_t*)(wsb + 163668224);
    bf16_t* Wt_proj= (bf16_t*)(wsb + 169959680);
    bf16_t* Wt_m1  = (bf16_t*)(wsb + 172056832);
    bf16_t* Wt_m2  = (bf16_t*)(wsb + 180445440);
    if (ws_size < (size_t)188834048) return;

    k_compact<<<NBATCH, 256, 0, stream>>>(mask, cnt, pidx);
    k_zerobias<<<4, 256, 0, stream>>>(zbias);
    k_init_query<<<dim3(NQ, NBATCH), 256, 0, stream>>>(emb, gauss, X);
    k_prompt_h<<<dim3(MASKN, NBATCH), 256, 0, stream>>>(depth, d2f_w1, d2f_b1, cnt, pidx, Qb);
    k_wt<<<dim3(16, 8), 256, 0, stream>>>(d2f_w2, Wt_qkv, 512, DIM);
    k_gemm_bt<0, float><<<dim3(8, 18, NBATCH), 256, 0, stream>>>(
        Qb, (size_t)MASKN * 512, 512, Wt_qkv, 512, d2f_b2,
        X + (size_t)1025 * DIM, (size_t)NMAX * DIM, DIM, 512, cnt, 0, MASKN);
    k_pe_prompt<<<dim3(MASKN, NBATCH), 256, 0, stream>>>(gauss, cnt, pidx, X);

    for (int i = 0; i < 2; ++i) {
        k_wt<<<dim3(48, 16), 256, 0, stream>>>(qkv_w  + (size_t)i * DIM * 3072, Wt_qkv,  DIM, 3072);
        k_wt<<<dim3(16, 16), 256, 0, stream>>>(proj_w + (size_t)i * DIM * DIM,  Wt_proj, DIM, DIM);
        k_wt<<<dim3(64, 16), 256, 0, stream>>>(mlp_w1 + (size_t)i * DIM * 4096, Wt_m1,   DIM, 4096);
        k_wt<<<dim3(16, 64), 256, 0, stream>>>(mlp_w2 + (size_t)i * 4096 * DIM, Wt_m2,   4096, DIM);

        k_sep<<<NBATCH, 256, 0, stream>>>(X, sep + (size_t)i * DIM);
        k_ln<<<dim3(NMAX, NBATCH), 256, 0, stream>>>(X, Xn, ln1_w + i * DIM, ln1_b + i * DIM, cnt);
        k_gemm_bt<0, bf16_t><<<dim3(24, 27, NBATCH), 256, 0, stream>>>(
            Xn, (size_t)NMAX * DIM, DIM, Wt_qkv, DIM, qkv_b + (size_t)i * 3072,
            Qb, (size_t)NMAX * 3072, 3072, DIM, cnt, 1025, NMAX);
        k_attn_mfma<<<dim3(27, NHEAD, NBATCH), 512, 0, stream>>>(Qb, Xn, cnt);
        k_gemm_bt<2, float><<<dim3(8, 27, NBATCH), 256, 0, stream>>>(
            Xn, (size_t)NMAX * DIM, DIM, Wt_proj, DIM, proj_b + (size_t)i * DIM,
            X, (size_t)NMAX * DIM, DIM, DIM, cnt, 1025, NMAX);
        k_ln<<<dim3(NMAX, NBATCH), 256, 0, stream>>>(X, Xn, ln2_w + i * DIM, ln2_b + i * DIM, cnt);
        for (int c = 0; c < 2; ++c) {
            k_gemm_bt<1, bf16_t><<<dim3(16, 27, NBATCH), 256, 0, stream>>>(
                Xn, (size_t)NMAX * DIM, DIM,
                Wt_m1 + (size_t)c * 2048 * DIM, DIM,
                mlp_b1 + (size_t)i * 4096 + c * 2048,
                Qb, (size_t)NMAX * 2048, 2048, DIM, cnt, 1025, NMAX);
            k_gemm_bt<2, float><<<dim3(8, 27, NBATCH), 256, 0, stream>>>(
                Qb, (size_t)NMAX * 2048, 2048,
                Wt_m2 + (size_t)c * 2048, 4096,
                (c == 0) ? (mlp_b2 + (size_t)i * DIM) : zbias,
                X, (size_t)NMAX * DIM, DIM, 2048, cnt, 1025, NMAX);
        }
    }

    k_out<<<dim3(NQ, NBATCH), 256, 0, stream>>>(X, emb, cnt, out);
    (void)in_sizes; (void)n_in; (void)out_size;
}

// Round 7
// 1609.756 us; speedup vs baseline: 1.2139x; 1.2139x over previous
//
#include <hip/hip_runtime.h>
#include <math.h>

#define NBATCH 4
#define DIM    1024
#define NHEAD  4
#define HD     256
#define NQ     1024
#define MASKN  2304           // 48*48
#define NMAX   3329           // 1024 query + 1 sep + 2304 max prompts
#define TWO_PI 6.283185307179586f

typedef unsigned short bf16_t;
typedef short bf16x8 __attribute__((ext_vector_type(8)));
typedef float f32x4  __attribute__((ext_vector_type(4)));

__device__ __forceinline__ float gelu_exact(float x) {
    return 0.5f * x * (1.0f + erff(x * 0.70710678118654752f));
}
__device__ __forceinline__ float bf2f(bf16_t h) {
    return __uint_as_float((unsigned)h << 16);
}
__device__ __forceinline__ bf16_t f2bf(float f) {   // round-to-nearest-even
    unsigned u = __float_as_uint(f);
    return (bf16_t)((u + 0x7FFFu + ((u >> 16) & 1u)) >> 16);
}
// async global->LDS, 16 B per lane; LDS dest = uniform base + lane*16
__device__ __forceinline__ void gload_lds16(const bf16_t* g, bf16_t* l) {
    __builtin_amdgcn_global_load_lds(
        (const __attribute__((address_space(1))) void*)g,
        (__attribute__((address_space(3))) void*)l, 16, 0, 0);
}

// ---------------------------------------------------------------- compaction
__global__ __launch_bounds__(256)
void k_compact(const int* __restrict__ mask, int* __restrict__ cnt, int* __restrict__ pidx) {
    int b = blockIdx.x;
    __shared__ int sc;
    if (threadIdx.x == 0) sc = 0;
    __syncthreads();
    for (int c = threadIdx.x; c < MASKN; c += blockDim.x)
        if (mask[b * MASKN + c] > 0) {
            int p = atomicAdd(&sc, 1);
            pidx[b * MASKN + p] = c;
        }
    __syncthreads();
    if (threadIdx.x == 0) cnt[b] = sc;
}

__global__ __launch_bounds__(256)
void k_zerobias(float* __restrict__ z) {
    z[blockIdx.x * 256 + threadIdx.x] = 0.f;
}

// ---------------------------------- weight transpose-convert: W(KxN f32)->Wt(NxK bf16)
__global__ __launch_bounds__(256)
void k_wt(const float* __restrict__ W, bf16_t* __restrict__ Wt, int K, int N) {
    __shared__ float T[64][65];
    int n0 = blockIdx.x * 64, k0 = blockIdx.y * 64;
    int tid = threadIdx.x;
    int lr = tid >> 4, lc = (tid & 15) * 4;
    #pragma unroll
    for (int i = 0; i < 4; ++i) {
        float4 v = *(const float4*)&W[(size_t)(k0 + lr + i * 16) * N + n0 + lc];
        T[lr + i * 16][lc + 0] = v.x; T[lr + i * 16][lc + 1] = v.y;
        T[lr + i * 16][lc + 2] = v.z; T[lr + i * 16][lc + 3] = v.w;
    }
    __syncthreads();
    int on = tid >> 2, ok = (tid & 3) * 16;
    bf16_t tmp[16];
    #pragma unroll
    for (int j = 0; j < 16; ++j) tmp[j] = f2bf(T[ok + j][on]);
    bf16_t* op = Wt + (size_t)(n0 + on) * K + k0 + ok;
    *(bf16x8*)op       = *(bf16x8*)&tmp[0];
    *(bf16x8*)(op + 8) = *(bf16x8*)&tmp[8];
}

// ------------------------------------------------- query tokens: emb + PE (f32 X)
__global__ __launch_bounds__(256)
void k_init_query(const float* __restrict__ emb, const float* __restrict__ gauss,
                  float* __restrict__ X) {
    int b = blockIdx.y, n = blockIdx.x, t = threadIdx.x;
    float fx = 2.0f * (((n & 31) + 0.5f) / 32.0f) - 1.0f;
    float fy = 2.0f * (((n >> 5) + 0.5f) / 32.0f) - 1.0f;
    const float* e = emb + ((size_t)b * NQ + n) * DIM;
    float* x = X + ((size_t)b * NMAX + n) * DIM;
    for (int d = t; d < 512; d += 256) {
        float ang = TWO_PI * (fx * gauss[d] + fy * gauss[512 + d]);
        float sn, cs; sincosf(ang, &sn, &cs);
        x[d]       = e[d] + sn;
        x[d + 512] = e[d + 512] + cs;
    }
}

// --------------------------------- prompt hidden: gelu(d*w1+b1) (M x 512) bf16
__global__ __launch_bounds__(256)
void k_prompt_h(const float* __restrict__ depth, const float* __restrict__ w1,
                const float* __restrict__ b1, const int* __restrict__ cnt,
                const int* __restrict__ pidx, bf16_t* __restrict__ Hp) {
    int b = blockIdx.y, s = blockIdx.x, t = threadIdx.x;
    bf16_t* hp = Hp + ((size_t)b * MASKN + s) * 512;
    if (s >= cnt[b]) { hp[t] = 0; hp[t + 256] = 0; return; }
    int cell = pidx[b * MASKN + s];
    float d = depth[b * MASKN + cell];
    for (int j = t; j < 512; j += 256)
        hp[j] = f2bf(gelu_exact(fmaf(d, w1[j], b1[j])));
}

// ------------------------------------------ add prompt PE into X rows (f32)
__global__ __launch_bounds__(256)
void k_pe_prompt(const float* __restrict__ gauss, const int* __restrict__ cnt,
                 const int* __restrict__ pidx, float* __restrict__ X) {
    int b = blockIdx.y, s = blockIdx.x, t = threadIdx.x;
    if (s >= cnt[b]) return;
    int cell = pidx[b * MASKN + s];
    int r = cell / 48, c = cell % 48;
    float fx = 2.0f * ((c + 0.5f) / 48.0f) - 1.0f;
    float fy = 2.0f * ((r + 0.5f) / 48.0f) - 1.0f;
    float* x = X + ((size_t)b * NMAX + 1025 + s) * DIM;
    for (int d = t; d < 512; d += 256) {
        float ang = TWO_PI * (fx * gauss[d] + fy * gauss[512 + d]);
        float sn, cs; sincosf(ang, &sn, &cs);
        x[d]       += sn;
        x[d + 512] += cs;
    }
}

// ---------------------------------------------------------------- sep token
__global__ __launch_bounds__(256)
void k_sep(float* __restrict__ X, const float* __restrict__ sep) {
    int b = blockIdx.x, t = threadIdx.x;
    float* x = X + ((size_t)b * NMAX + 1024) * DIM;
    *(float4*)&x[t * 4] = *(const float4*)&sep[t * 4];
}

// -------------------------------------------------- layernorm: X f32 -> Xn bf16
__global__ __launch_bounds__(256)
void k_ln(const float* __restrict__ X, bf16_t* __restrict__ Xn,
          const float* __restrict__ w, const float* __restrict__ bb,
          const int* __restrict__ cnt) {
    int b = blockIdx.y, n = blockIdx.x;
    int Nb = 1025 + cnt[b];
    if (n >= Nb) return;
    int t = threadIdx.x;
    const float* x = X + ((size_t)b * NMAX + n) * DIM;
    float4 v = *(const float4*)&x[t * 4];
    float s = v.x + v.y + v.z + v.w;
    float q = v.x * v.x + v.y * v.y + v.z * v.z + v.w * v.w;
    #pragma unroll
    for (int off = 32; off > 0; off >>= 1) {
        s += __shfl_xor(s, off);
        q += __shfl_xor(q, off);
    }
    __shared__ float ss[4], sq[4];
    int wave = t >> 6, lane = t & 63;
    if (lane == 0) { ss[wave] = s; sq[wave] = q; }
    __syncthreads();
    s = ss[0] + ss[1] + ss[2] + ss[3];
    q = sq[0] + sq[1] + sq[2] + sq[3];
    float mean = s * (1.0f / DIM);
    float var  = q * (1.0f / DIM) - mean * mean;
    float rstd = 1.0f / sqrtf(var + 1e-5f);
    float4 ww = *(const float4*)&w[t * 4];
    float4 b4 = *(const float4*)&bb[t * 4];
    ushort4 o;
    o.x = f2bf((v.x - mean) * rstd * ww.x + b4.x);
    o.y = f2bf((v.y - mean) * rstd * ww.y + b4.y);
    o.z = f2bf((v.z - mean) * rstd * ww.z + b4.z);
    o.w = f2bf((v.w - mean) * rstd * ww.w + b4.w);
    *(ushort4*)&(Xn + ((size_t)b * NMAX + n) * DIM)[t * 4] = o;
}

// ================================ MFMA GEMM: A bf16 @ Wt bf16 (pre-transposed)
// 128x128 tile, BK=64, 4 waves x 64x64. No-pad swizzled LDS [128 rows][64 k]:
// 16B chunk c of row r holds global k-chunk c ^ (r&7). Staged with
// global_load_lds width=16 (uniform base + lane*16).
template <int EPI, typename OutT>
__global__ __launch_bounds__(256)
void k_gemm_bt(const bf16_t* __restrict__ A, size_t bsA, int ldA,
               const bf16_t* __restrict__ Wt, int ldWt, const float* __restrict__ bias,
               OutT* __restrict__ Out, size_t bsO, int ldO,
               int K, const int* __restrict__ cnt, int bound_add, int rows_phys) {
    int b = blockIdx.z;
    int bound = cnt[b] + bound_add;
    int tr = blockIdx.y * 128;
    if (tr >= bound) return;
    int tc = blockIdx.x * 128;

    __shared__ bf16_t As[128 * 64];
    __shared__ bf16_t Bs[128 * 64];

    int tid  = threadIdx.x;
    int wave = tid >> 6, lane = tid & 63;
    int quad = lane >> 4, l16 = lane & 15;
    int wr = (wave >> 1) * 64, wc = (wave & 1) * 64;
    int sw = l16 & 7;   // read swizzle

    f32x4 acc[4][4];
    #pragma unroll
    for (int mi = 0; mi < 4; ++mi)
        #pragma unroll
        for (int ni = 0; ni < 4; ++ni)
            acc[mi][ni] = (f32x4){0.f, 0.f, 0.f, 0.f};

    const bf16_t* Ab = A + (size_t)b * bsA;
    // staging geometry: call j, lane l -> row = wave*32 + j*8 + (l>>3),
    // lds chunk = l&7, global chunk g = (l&7) ^ (row&7)
    int srow[4], sg[4];
    #pragma unroll
    for (int j = 0; j < 4; ++j) {
        srow[j] = (wave << 5) + (j << 3) + (lane >> 3);
        sg[j]   = (lane & 7) ^ (srow[j] & 7);
    }

    for (int k0 = 0; k0 < K; k0 += 64) {
        __syncthreads();
        #pragma unroll
        for (int j = 0; j < 4; ++j) {
            int arow = tr + srow[j];
            if (arow >= rows_phys) arow = rows_phys - 1;   // garbage ok: C rows unstored
            gload_lds16(Ab + (size_t)arow * ldA + k0 + sg[j] * 8,
                        As + (wave << 11) + (j << 9));
            gload_lds16(Wt + (size_t)(tc + srow[j]) * ldWt + k0 + sg[j] * 8,
                        Bs + (wave << 11) + (j << 9));
        }
        __syncthreads();

        #pragma unroll
        for (int half = 0; half < 2; ++half) {
            bf16x8 af[4], bfr[4];
            #pragma unroll
            for (int mi = 0; mi < 4; ++mi) {
                int r = wr + mi * 16 + l16;
                int ch = ((half << 2) + quad) ^ sw;
                af[mi] = *(const bf16x8*)&As[r * 64 + ch * 8];
            }
            #pragma unroll
            for (int ni = 0; ni < 4; ++ni) {
                int r = wc + ni * 16 + l16;
                int ch = ((half << 2) + quad) ^ sw;
                bfr[ni] = *(const bf16x8*)&Bs[r * 64 + ch * 8];
            }
            #pragma unroll
            for (int mi = 0; mi < 4; ++mi)
                #pragma unroll
                for (int ni = 0; ni < 4; ++ni)
                    acc[mi][ni] = __builtin_amdgcn_mfma_f32_16x16x32_bf16(
                        af[mi], bfr[ni], acc[mi][ni], 0, 0, 0);
        }
    }

    OutT* Ob = Out + (size_t)b * bsO;
    #pragma unroll
    for (int ni = 0; ni < 4; ++ni) {
        int col = tc + wc + ni * 16 + l16;
        float bs = bias[col];
        #pragma unroll
        for (int mi = 0; mi < 4; ++mi) {
            int row0 = tr + wr + mi * 16 + quad * 4;
            #pragma unroll
            for (int r = 0; r < 4; ++r) {
                int row = row0 + r;
                if (row >= rows_phys) continue;
                float v = acc[mi][ni][r] + bs;
                if (EPI == 1) v = gelu_exact(v);
                OutT* op = Ob + (size_t)row * ldO + col;
                if (EPI == 2) v += *(const float*)op;
                if (sizeof(OutT) == 2) *(bf16_t*)op = f2bf(v);
                else                   *(float*)op  = v;
            }
        }
    }
}

// =================================================== MFMA flash attention
// R5 shape: 64 Q rows/WG, 256 thr (4 waves x 16 rows). K-tile 32x256 no-pad,
// swizzled (chunk ^ (key&7)), staged via global_load_lds (OOB keys clamped —
// their P columns are masked to 0). V transposed per-lane as in R5.
__global__ __launch_bounds__(256)
void k_attn_mfma(const bf16_t* __restrict__ QKV, bf16_t* __restrict__ O,
                 const int* __restrict__ cnt) {
    int b = blockIdx.z, h = blockIdx.y;
    int Nb = 1025 + cnt[b];
    int qbase = blockIdx.x * 64;
    if (qbase >= Nb) return;

    __shared__ bf16_t Kt[32 * 256];     // 16 KB swizzled
    __shared__ bf16_t Vt[256][40];      // 20.5 KB transposed
    __shared__ bf16_t Pt[4][16][40];    // 5.1 KB per-wave P

    int tid  = threadIdx.x;
    int wave = tid >> 6, lane = tid & 63;
    int quad = lane >> 4, l16 = lane & 15;
    int sw = l16 & 7;

    int qrow  = qbase + wave * 16 + l16;
    int qrowc = qrow < NMAX ? qrow : NMAX - 1;
    const bf16_t* Qp = QKV + (size_t)b * NMAX * 3072 + (size_t)qrowc * 3072 + h * HD;
    bf16x8 qf[8];
    #pragma unroll
    for (int c = 0; c < 8; ++c)
        qf[c] = *(const bf16x8*)(Qp + c * 32 + quad * 8);

    f32x4 Oacc[16];
    #pragma unroll
    for (int n = 0; n < 16; ++n) Oacc[n] = (f32x4){0.f, 0.f, 0.f, 0.f};
    float l[4] = {0.f, 0.f, 0.f, 0.f};

    const bf16_t* Kg = QKV + (size_t)b * NMAX * 3072 + 1024 + h * HD;
    const bf16_t* Vg = QKV + (size_t)b * NMAX * 3072 + 2048 + h * HD;

    // K staging: call j, lane -> row = wave*8 + j*2 + (lane>>5), chunk = lane&31,
    // global chunk g = chunk ^ (row&7)
    int krow[4], kg[4];
    #pragma unroll
    for (int j = 0; j < 4; ++j) {
        krow[j] = (wave << 3) + (j << 1) + (lane >> 5);
        kg[j]   = (lane & 31) ^ (krow[j] & 7);
    }
    int vd_s = (tid >> 3) * 8;    // V: 8 dims, 4 keys per thread
    int vr_s = (tid & 7) * 4;

    for (int kt = 0; kt < Nb; kt += 32) {
        __syncthreads();
        #pragma unroll
        for (int j = 0; j < 4; ++j) {
            int gk = kt + krow[j];
            if (gk >= Nb) gk = Nb - 1;    // garbage ok: P column masked
            gload_lds16(Kg + (size_t)gk * 3072 + kg[j] * 8,
                        Kt + (wave << 11) + (j << 9));
        }
        {   // V tile transposed (zero-filled OOB)
            bf16x8 vv[4];
            #pragma unroll
            for (int r = 0; r < 4; ++r) {
                int gk = kt + vr_s + r;
                vv[r] = (bf16x8){0,0,0,0,0,0,0,0};
                if (gk < Nb) vv[r] = *(const bf16x8*)(Vg + (size_t)gk * 3072 + vd_s);
            }
            #pragma unroll
            for (int j = 0; j < 8; ++j) {
                ushort4 pk;
                pk.x = (unsigned short)vv[0][j];
                pk.y = (unsigned short)vv[1][j];
                pk.z = (unsigned short)vv[2][j];
                pk.w = (unsigned short)vv[3][j];
                *(ushort4*)&Vt[vd_s + j][vr_s] = pk;
            }
        }
        __syncthreads();

        // S = Q.K^T  (swizzled Kt reads)
        f32x4 c0 = (f32x4){0.f,0.f,0.f,0.f}, c1 = (f32x4){0.f,0.f,0.f,0.f};
        #pragma unroll
        for (int c = 0; c < 8; ++c) {
            int ch = ((c << 2) + quad) ^ sw;
            bf16x8 kb0 = *(const bf16x8*)&Kt[l16 * 256 + ch * 8];
            bf16x8 kb1 = *(const bf16x8*)&Kt[(l16 + 16) * 256 + ch * 8];
            c0 = __builtin_amdgcn_mfma_f32_16x16x32_bf16(qf[c], kb0, c0, 0, 0, 0);
            c1 = __builtin_amdgcn_mfma_f32_16x16x32_bf16(qf[c], kb1, c1, 0, 0, 0);
        }
        float ls[4];
        #pragma unroll
        for (int r = 0; r < 4; ++r) {
            float p0 = (kt + l16      < Nb) ? __expf(c0[r] * 0.0625f) : 0.f;
            float p1 = (kt + 16 + l16 < Nb) ? __expf(c1[r] * 0.0625f) : 0.f;
            Pt[wave][quad * 4 + r][l16]      = f2bf(p0);
            Pt[wave][quad * 4 + r][l16 + 16] = f2bf(p1);
            ls[r] = p0 + p1;
        }
        #pragma unroll
        for (int off = 1; off < 16; off <<= 1)
            #pragma unroll
            for (int r = 0; r < 4; ++r)
                ls[r] += __shfl_xor(ls[r], off);
        #pragma unroll
        for (int r = 0; r < 4; ++r) l[r] += ls[r];

        // P.V
        bf16x8 pa = *(const bf16x8*)&Pt[wave][l16][quad * 8];
        #pragma unroll
        for (int n = 0; n < 16; ++n) {
            bf16x8 vb = *(const bf16x8*)&Vt[n * 16 + l16][quad * 8];
            Oacc[n] = __builtin_amdgcn_mfma_f32_16x16x32_bf16(pa, vb, Oacc[n], 0, 0, 0);
        }
    }

    float inv[4];
    #pragma unroll
    for (int r = 0; r < 4; ++r) inv[r] = 1.0f / l[r];
    bf16_t* Op = O + (size_t)b * NMAX * DIM + h * HD;
    #pragma unroll
    for (int r = 0; r < 4; ++r) {
        int row = qbase + wave * 16 + quad * 4 + r;
        if (row < Nb) {
            bf16_t* op = Op + (size_t)row * DIM;
            #pragma unroll
            for (int n = 0; n < 16; ++n)
                op[n * 16 + l16] = f2bf(Oacc[n][r] * inv[r]);
        }
    }
}

// ---------------------------------------------------------------- output
__global__ __launch_bounds__(256)
void k_out(const float* __restrict__ X, const float* __restrict__ emb,
           const int* __restrict__ cnt, float* __restrict__ out) {
    int b = blockIdx.y, n = blockIdx.x, t = threadIdx.x;
    const float* s = (cnt[b] > 0) ? X + ((size_t)b * NMAX + n) * DIM
                                  : emb + ((size_t)b * NQ + n) * DIM;
    *(float4*)&out[((size_t)b * NQ + n) * DIM + t * 4] = *(const float4*)&s[t * 4];
}

// ============================================================== launch
extern "C" void kernel_launch(void* const* d_in, const int* in_sizes, int n_in,
                              void* d_out, int out_size, void* d_ws, size_t ws_size,
                              hipStream_t stream) {
    const float* emb    = (const float*)d_in[0];
    const float* depth  = (const float*)d_in[1];
    const int*   mask   = (const int*)d_in[2];
    const float* gauss  = (const float*)d_in[5];
    const float* d2f_w1 = (const float*)d_in[6];
    const float* d2f_b1 = (const float*)d_in[7];
    const float* d2f_w2 = (const float*)d_in[8];
    const float* d2f_b2 = (const float*)d_in[9];
    const float* sep    = (const float*)d_in[10];
    const float* ln1_w  = (const float*)d_in[11];
    const float* ln1_b  = (const float*)d_in[12];
    const float* qkv_w  = (const float*)d_in[13];
    const float* qkv_b  = (const float*)d_in[14];
    const float* proj_w = (const float*)d_in[15];
    const float* proj_b = (const float*)d_in[16];
    const float* ln2_w  = (const float*)d_in[17];
    const float* ln2_b  = (const float*)d_in[18];
    const float* mlp_w1 = (const float*)d_in[19];
    const float* mlp_b1 = (const float*)d_in[20];
    const float* mlp_w2 = (const float*)d_in[21];
    const float* mlp_b2 = (const float*)d_in[22];
    float* out = (float*)d_out;

    char* wsb = (char*)d_ws;
    int*    cnt   = (int*)wsb;
    int*    pidx  = (int*)(wsb + 256);
    float*  zbias = (float*)(wsb + 37120);
    float*  X     = (float*)(wsb + 41216);
    bf16_t* Xn    = (bf16_t*)(wsb + 54583552);
    bf16_t* Qb    = (bf16_t*)(wsb + 81854720);
    bf16_t* Wt_qkv = (bf16_t*)(wsb + 163668224);
    bf16_t* Wt_proj= (bf16_t*)(wsb + 169959680);
    bf16_t* Wt_m1  = (bf16_t*)(wsb + 172056832);
    bf16_t* Wt_m2  = (bf16_t*)(wsb + 180445440);
    if (ws_size < (size_t)188834048) return;

    k_compact<<<NBATCH, 256, 0, stream>>>(mask, cnt, pidx);
    k_zerobias<<<4, 256, 0, stream>>>(zbias);
    k_init_query<<<dim3(NQ, NBATCH), 256, 0, stream>>>(emb, gauss, X);
    k_prompt_h<<<dim3(MASKN, NBATCH), 256, 0, stream>>>(depth, d2f_w1, d2f_b1, cnt, pidx, Qb);
    k_wt<<<dim3(16, 8), 256, 0, stream>>>(d2f_w2, Wt_qkv, 512, DIM);
    k_gemm_bt<0, float><<<dim3(8, 18, NBATCH), 256, 0, stream>>>(
        Qb, (size_t)MASKN * 512, 512, Wt_qkv, 512, d2f_b2,
        X + (size_t)1025 * DIM, (size_t)NMAX * DIM, DIM, 512, cnt, 0, MASKN);
    k_pe_prompt<<<dim3(MASKN, NBATCH), 256, 0, stream>>>(gauss, cnt, pidx, X);

    for (int i = 0; i < 2; ++i) {
        k_wt<<<dim3(48, 16), 256, 0, stream>>>(qkv_w  + (size_t)i * DIM * 3072, Wt_qkv,  DIM, 3072);
        k_wt<<<dim3(16, 16), 256, 0, stream>>>(proj_w + (size_t)i * DIM * DIM,  Wt_proj, DIM, DIM);
        k_wt<<<dim3(64, 16), 256, 0, stream>>>(mlp_w1 + (size_t)i * DIM * 4096, Wt_m1,   DIM, 4096);
        k_wt<<<dim3(16, 64), 256, 0, stream>>>(mlp_w2 + (size_t)i * 4096 * DIM, Wt_m2,   4096, DIM);

        k_sep<<<NBATCH, 256, 0, stream>>>(X, sep + (size_t)i * DIM);
        k_ln<<<dim3(NMAX, NBATCH), 256, 0, stream>>>(X, Xn, ln1_w + i * DIM, ln1_b + i * DIM, cnt);
        k_gemm_bt<0, bf16_t><<<dim3(24, 27, NBATCH), 256, 0, stream>>>(
            Xn, (size_t)NMAX * DIM, DIM, Wt_qkv, DIM, qkv_b + (size_t)i * 3072,
            Qb, (size_t)NMAX * 3072, 3072, DIM, cnt, 1025, NMAX);
        k_attn_mfma<<<dim3(53, NHEAD, NBATCH), 256, 0, stream>>>(Qb, Xn, cnt);
        k_gemm_bt<2, float><<<dim3(8, 27, NBATCH), 256, 0, stream>>>(
            Xn, (size_t)NMAX * DIM, DIM, Wt_proj, DIM, proj_b + (size_t)i * DIM,
            X, (size_t)NMAX * DIM, DIM, DIM, cnt, 1025, NMAX);
        k_ln<<<dim3(NMAX, NBATCH), 256, 0, stream>>>(X, Xn, ln2_w + i * DIM, ln2_b + i * DIM, cnt);
        for (int c = 0; c < 2; ++c) {
            k_gemm_bt<1, bf16_t><<<dim3(16, 27, NBATCH), 256, 0, stream>>>(
                Xn, (size_t)NMAX * DIM, DIM,
                Wt_m1 + (size_t)c * 2048 * DIM, DIM,
                mlp_b1 + (size_t)i * 4096 + c * 2048,
                Qb, (size_t)NMAX * 2048, 2048, DIM, cnt, 1025, NMAX);
            k_gemm_bt<2, float><<<dim3(8, 27, NBATCH), 256, 0, stream>>>(
                Qb, (size_t)NMAX * 2048, 2048,
                Wt_m2 + (size_t)c * 2048, 4096,
                (c == 0) ? (mlp_b2 + (size_t)i * DIM) : zbias,
                X, (size_t)NMAX * DIM, DIM, 2048, cnt, 1025, NMAX);
        }
    }

    k_out<<<dim3(NQ, NBATCH), 256, 0, stream>>>(X, emb, cnt, out);
    (void)in_sizes; (void)n_in; (void)out_size;
}